// Round 14
// baseline (98.031 us; speedup 1.0000x reference)
//
#include <hip/hip_runtime.h>
#include <hip/hip_bf16.h>

typedef __bf16 bf16_t;
typedef __attribute__((ext_vector_type(4))) float f32x4;
typedef __attribute__((ext_vector_type(8))) __bf16 bf16x8;
typedef __attribute__((ext_vector_type(4))) __bf16 bf16x4;
typedef __attribute__((ext_vector_type(2))) __bf16 bf16x2;

#define NQ    1024
#define DIM   384
#define NHEAD 8
#define HDIM  48
#define HALFD 24
#define NKEY  196
#define TOTAL 5440   // 64*64 + 32*32 + 16*16 + 8*8

typedef __attribute__((address_space(1))) void gas_void;
typedef __attribute__((address_space(3))) void las_void;
__device__ __forceinline__ void gload16(const void* g, void* l) {
    __builtin_amdgcn_global_load_lds((gas_void*)g, (las_void*)l, 16, 0, 0);
}

// ---------------------------------------------------------------------------
// prep: fmaps fp32->bf16 (blocks [0,nfm)), weights (nfm..nfm+575),
// sincos tables (block nfm+576).
// ---------------------------------------------------------------------------
__global__ __launch_bounds__(256) void prep_kernel(
    const float* __restrict__ fmaps, bf16_t* __restrict__ fm_bf, int nfm,
    const float* __restrict__ wq, const float* __restrict__ wkv,
    const float* __restrict__ wout, bf16_t* __restrict__ wq_bf,
    bf16_t* __restrict__ wkv_bf, bf16_t* __restrict__ wout_bf,
    float2* __restrict__ tabS, float2* __restrict__ tabL)
{
    int bid = blockIdx.x;
    if (bid < nfm) {
        int i = bid * 256 + threadIdx.x;
        float4 v = ((const float4*)fmaps)[i];
        bf16x4 o = { (bf16_t)v.x, (bf16_t)v.y, (bf16_t)v.z, (bf16_t)v.w };
        ((bf16x4*)fm_bf)[i] = o;
        return;
    }
    int wb = bid - nfm;
    if (wb == 576) {
        int t = threadIdx.x;
        if (t < 512) {
            int i = t >> 3, f = t & 7;
            float fr = powf(10.f, -(float)f / 8.f);
            float s, c; sincosf((float)i * fr, &s, &c);
            tabS[t] = make_float2(c, s);
        } else if (t < 544) {
            int u = t - 512; int l = u >> 3, f = u & 7;
            float fr = powf(10.f, (float)f / 8.f);
            float s, c; sincosf((float)l * fr, &s, &c);
            tabL[u] = make_float2(c, s);
        }
        return;
    }
    int i = wb * 256 + threadIdx.x;
    const float* src; bf16_t* dst; int off;
    if (i < 36864)       { src = wq;   dst = wq_bf;   off = i; }
    else if (i < 110592) { src = wkv;  dst = wkv_bf;  off = i - 36864; }
    else                 { src = wout; dst = wout_bf; off = i - 110592; }
    float4 v = ((const float4*)src)[off];
    bf16x4 o = { (bf16_t)v.x, (bf16_t)v.y, (bf16_t)v.z, (bf16_t)v.w };
    ((bf16x4*)dst)[off] = o;
}

// ---------------------------------------------------------------------------
// bf16 NT GEMM (global_load_lds + swizzle, XCD block swizzle) — R7-proven.
// EPI: 0 = fp32 C, 1 = fp32 C + resid, 2 = bf16 C.  BT = 128 or 64.
// ---------------------------------------------------------------------------
template<int EPI, int BT>
__global__ __launch_bounds__(256) void gemm_bf16(
    const bf16_t* __restrict__ A, const bf16_t* __restrict__ Bw,
    void* __restrict__ Cp, const float* __restrict__ resid,
    int M, int Nout, int K)
{
    constexpr int FRG = BT / 32;
    constexpr int WT  = BT / 2;
    __shared__ bf16_t As[BT * 64];
    __shared__ bf16_t Bs[BT * 64];
    const int tid = threadIdx.x;

    const int bid = blockIdx.y * gridDim.x + blockIdx.x;
    const int nwg = gridDim.x * gridDim.y;
    const int qq = nwg >> 3, rr8 = nwg & 7;
    const int xcd = bid & 7, loc = bid >> 3;
    const int swz = (xcd < rr8 ? xcd * (qq + 1) : rr8 * (qq + 1) + (xcd - rr8) * qq) + loc;
    const int bm = swz / gridDim.x, bn = swz % gridDim.x;

    const int wave = tid >> 6, lane = tid & 63;
    const int wr   = wave >> 1, wc = wave & 1;
    const int fr   = lane & 15, g = lane >> 4;

    f32x4 acc[FRG][FRG];
#pragma unroll
    for (int i = 0; i < FRG; ++i)
#pragma unroll
        for (int j = 0; j < FRG; ++j) acc[i][j] = (f32x4){0.f, 0.f, 0.f, 0.f};

    const bf16_t* Ab = A  + (size_t)bm * BT * K;
    const bf16_t* Bb = Bw + (size_t)bn * BT * K;

    for (int kt = 0; kt < K; kt += 64) {
        __syncthreads();
#pragma unroll
        for (int it = 0; it < BT / 32; ++it) {
            int chunk = it * 256 + tid;
            int row = chunk >> 3, c8 = chunk & 7;
            int sc8 = c8 ^ (row & 7);
            gload16(Ab + (size_t)row * K + kt + sc8 * 8, As + chunk * 8);
            gload16(Bb + (size_t)row * K + kt + sc8 * 8, Bs + chunk * 8);
        }
        __syncthreads();
#pragma unroll
        for (int kk = 0; kk < 2; ++kk) {
            bf16x8 af[FRG], bfr[FRG];
#pragma unroll
            for (int mi = 0; mi < FRG; ++mi) {
                int row = wr * WT + mi * 16 + fr;
                int c = (kk * 4 + g) ^ (row & 7);
                af[mi] = *(const bf16x8*)(As + row * 64 + c * 8);
            }
#pragma unroll
            for (int ni = 0; ni < FRG; ++ni) {
                int row = wc * WT + ni * 16 + fr;
                int c = (kk * 4 + g) ^ (row & 7);
                bfr[ni] = *(const bf16x8*)(Bs + row * 64 + c * 8);
            }
#pragma unroll
            for (int mi = 0; mi < FRG; ++mi)
#pragma unroll
                for (int ni = 0; ni < FRG; ++ni)
                    acc[mi][ni] = __builtin_amdgcn_mfma_f32_16x16x32_bf16(
                        af[mi], bfr[ni], acc[mi][ni], 0, 0, 0);
        }
    }

    const int r0 = g << 2;
#pragma unroll
    for (int mi = 0; mi < FRG; ++mi) {
#pragma unroll
        for (int ni = 0; ni < FRG; ++ni) {
#pragma unroll
            for (int e = 0; e < 4; ++e) {
                int row = bm * BT + wr * WT + mi * 16 + r0 + e;
                int col = bn * BT + wc * WT + ni * 16 + fr;
                float v = acc[mi][ni][e];
                if (EPI == 2) {
                    ((bf16_t*)Cp)[(size_t)row * Nout + col] = (bf16_t)v;
                } else {
                    if (EPI == 1) v += resid[(size_t)row * Nout + col];
                    ((float*)Cp)[(size_t)row * Nout + col] = v;
                }
            }
        }
    }
}

// ---------------------------------------------------------------------------
__global__ __launch_bounds__(64) void ln_kernel(
    const float* __restrict__ q, const float* __restrict__ w,
    const float* __restrict__ b, bf16_t* __restrict__ xout)
{
    const int n = blockIdx.x, lane = threadIdx.x;
    const float* row = q + (size_t)n * DIM;
    float v[6], s = 0.f, s2 = 0.f;
#pragma unroll
    for (int i = 0; i < 6; ++i) {
        v[i] = row[lane + i * 64];
        s += v[i]; s2 += v[i] * v[i];
    }
#pragma unroll
    for (int m = 32; m; m >>= 1) { s += __shfl_xor(s, m); s2 += __shfl_xor(s2, m); }
    float mu  = s * (1.f / DIM);
    float var = s2 * (1.f / DIM) - mu * mu;
    float rs  = rsqrtf(var + 1e-5f);
#pragma unroll
    for (int i = 0; i < 6; ++i) {
        int d = lane + i * 64;
        xout[(size_t)n * DIM + d] = (bf16_t)((v[i] - mu) * rs * w[d] + b[d]);
    }
}

// ---------------------------------------------------------------------------
// Pre-rotate the k-half of the kv map in place. One thread per (row, head).
// ---------------------------------------------------------------------------
__global__ __launch_bounds__(256) void rope_k_kernel(
    bf16_t* __restrict__ kvm, const float2* __restrict__ tabS,
    const float2* __restrict__ tabL, int Mkv)
{
    int t = blockIdx.x * 256 + threadIdx.x;
    if (t >= Mkv * NHEAD) return;
    int row = t >> 3, h = t & 7;

    int rr = row % TOTAL;
    int l, i, j;
    if (rr < 4096)      { l = 0; i = rr >> 6;               j = rr & 63; }
    else if (rr < 5120) { l = 1; int u = rr - 4096; i = u >> 5; j = u & 31; }
    else if (rr < 5376) { l = 2; int u = rr - 5120; i = u >> 4; j = u & 15; }
    else                { l = 3; int u = rr - 5376; i = u >> 3; j = u & 7;  }

    bf16_t* base = kvm + (size_t)row * (2 * DIM) + h * HDIM;
    bf16x8 xa[3], xb[3];
#pragma unroll
    for (int k = 0; k < 3; ++k) {
        xa[k] = *(const bf16x8*)(base + 8 * k);
        xb[k] = *(const bf16x8*)(base + HALFD + 8 * k);
    }
#pragma unroll
    for (int d = 0; d < HALFD; ++d) {
        float2 cs = (d < 8) ? tabS[i * 8 + d]
                  : (d < 16) ? tabS[j * 8 + (d - 8)]
                             : tabL[l * 8 + (d - 16)];
        float x1 = (float)xa[d >> 3][d & 7];
        float x2 = (float)xb[d >> 3][d & 7];
        xa[d >> 3][d & 7] = (bf16_t)(x1 * cs.x - x2 * cs.y);
        xb[d >> 3][d & 7] = (bf16_t)(x1 * cs.y + x2 * cs.x);
    }
#pragma unroll
    for (int k = 0; k < 3; ++k) {
        *(bf16x8*)(base + 8 * k)         = xa[k];
        *(bf16x8*)(base + HALFD + 8 * k) = xb[k];
    }
}

// ---------------------------------------------------------------------------
// Attention: one block (256 threads) per query.
// XCD-chunked query remap (R7) + register-score shuffle-softmax (R6) +
// 16B-load V phase (R13). Three barriers total.
// ---------------------------------------------------------------------------
__global__ __launch_bounds__(256) void attn_kernel(
    const float* __restrict__ qproj,   // (N,384) pre-RoPE fp32
    const int*   __restrict__ pos,     // (N,4) b,i,j,l
    const bf16_t* __restrict__ kvm,    // (B*total, 768) bf16, k pre-rotated
    const float2* __restrict__ tabS, const float2* __restrict__ tabL,
    bf16_t* __restrict__ attn_out)     // (N,384) bf16
{
    __shared__ float qs[DIM];
    __shared__ float sc[NHEAD * NKEY];
    __shared__ int   flatL[NKEY];      // flat | (invalid << 30)
    __shared__ float ptv[5][DIM];

    const int bid = blockIdx.x, tid = threadIdx.x;
    const int n = ((bid & 7) << 7) | (bid >> 3);   // XCD-chunked remap
    const int b  = pos[n * 4 + 0];
    const int qi = pos[n * 4 + 1];
    const int qj = pos[n * 4 + 2];
    const int ql = pos[n * 4 + 3];

    // q RoPE (threads 0..191) | integer geometry (threads 192..255)
    if (tid < 192) {
        int h = tid / HALFD, d = tid - (tid / HALFD) * HALFD;
        float2 cs = (d < 8) ? tabS[qi * 8 + d]
                  : (d < 16) ? tabS[qj * 8 + (d - 8)]
                             : tabL[ql * 8 + (d - 16)];
        float x1 = qproj[(size_t)n * DIM + h * HDIM + d];
        float x2 = qproj[(size_t)n * DIM + h * HDIM + HALFD + d];
        qs[h * HDIM + d]         = x1 * cs.x - x2 * cs.y;
        qs[h * HDIM + HALFD + d] = x1 * cs.y + x2 * cs.x;
    } else {
        for (int kk = tid - 192; kk < NKEY; kk += 64) {
            int l = kk / 49, rem = kk - l * 49;
            int a = rem / 7, bb2 = rem - a * 7;
            int Hl = 64 >> l;
            int off = (l == 0) ? 0 : (l == 1) ? 4096 : (l == 2) ? 5120 : 5376;
            int e = ql - l;
            int ti = 2 * qi + 1, tj = 2 * qj + 1;
            int ci = (e >= 1) ? (ti << (e - 1)) : (ti >> (1 - e));
            int cj = (e >= 1) ? (tj << (e - 1)) : (tj >> (1 - e));
            int ii = ci + a - 3, jj = cj + bb2 - 3;
            int valid = (ii >= 0) && (ii < Hl) && (jj >= 0) && (jj < Hl);
            ii = min(max(ii, 0), Hl - 1); jj = min(max(jj, 0), Hl - 1);
            flatL[kk] = (off + ii * Hl + jj) | (valid ? 0 : (1 << 30));
        }
    }
    __syncthreads();                       // barrier 1

    const size_t bbase = (size_t)b * TOTAL;
    const int wave = tid >> 6, lane = tid & 63;

    // scores in registers: wave w handles heads 2w, 2w+1; 4 keys/lane;
    // softmax via wave shuffles only.
#pragma unroll
    for (int p = 0; p < 2; ++p) {
        const int h = wave * 2 + p;
        float qreg[HDIM];
#pragma unroll
        for (int i = 0; i < HDIM; ++i) qreg[i] = qs[h * HDIM + i];  // broadcast
        float s0[4];
#pragma unroll
        for (int s = 0; s < 4; ++s) {
            int key = s * 64 + lane;
            s0[s] = -1e30f;
            if (key < NKEY) {
                int fv = flatL[key];
                int flat = fv & 0x3fffffff;
                const bf16_t* krow = kvm + (bbase + (size_t)flat) * (2 * DIM) + h * HDIM;
                bf16x8 kv[6];
#pragma unroll
                for (int i = 0; i < 6; ++i) kv[i] = *(const bf16x8*)(krow + i * 8);
                float dot = 0.f;
#pragma unroll
                for (int i = 0; i < 6; ++i)
#pragma unroll
                    for (int e2 = 0; e2 < 8; ++e2)
                        dot += (float)kv[i][e2] * qreg[i * 8 + e2];
                s0[s] = (fv & (1 << 30)) ? -1e9f : dot * 0.14433756729740643f;
            }
        }
        float m = fmaxf(fmaxf(s0[0], s0[1]), fmaxf(s0[2], s0[3]));
#pragma unroll
        for (int o = 32; o; o >>= 1) m = fmaxf(m, __shfl_xor(m, o));
        float e0 = __expf(s0[0] - m), e1 = __expf(s0[1] - m);
        float e2 = __expf(s0[2] - m), e3 = __expf(s0[3] - m);
        float sum = e0 + e1 + e2 + e3;
#pragma unroll
        for (int o = 32; o; o >>= 1) sum += __shfl_xor(sum, o);
        float inv = 1.f / sum;
        sc[h * NKEY + lane]       = e0 * inv;
        sc[h * NKEY + 64 + lane]  = e1 * inv;
        sc[h * NKEY + 128 + lane] = e2 * inv;
        if (lane < 4) sc[h * NKEY + 192 + lane] = e3 * inv;
    }
    __syncthreads();                       // barrier 2

    // V accumulation: 240 threads = 5 key-groups x 48 dim-octets (16B loads)
    if (tid < 240) {
        int g5 = tid / 48, o = tid - (tid / 48) * 48;  // key-group, dim-octet
        int h = o / 6;                                  // head of this octet
        float a[8];
#pragma unroll
        for (int e = 0; e < 8; ++e) a[e] = 0.f;
        const float* sch = sc + h * NKEY;
#pragma unroll 4
        for (int kk = g5; kk < NKEY; kk += 5) {
            float w = sch[kk];
            bf16x8 vv = *(const bf16x8*)(kvm + (bbase + (size_t)(flatL[kk] & 0x3fffffff)) * (2 * DIM)
                                         + DIM + 8 * o);
#pragma unroll
            for (int e = 0; e < 8; ++e) a[e] += w * (float)vv[e];
        }
        float4 lo = { a[0], a[1], a[2], a[3] };
        float4 hi = { a[4], a[5], a[6], a[7] };
        *(float4*)(&ptv[g5][8 * o])     = lo;
        *(float4*)(&ptv[g5][8 * o + 4]) = hi;
    }
    __syncthreads();                       // barrier 3

    // final reduce over key-groups: 192 threads x 2 dims
    if (tid < 192) {
        int d0 = 2 * tid;
        float s0 = 0.f, s1 = 0.f;
#pragma unroll
        for (int g5 = 0; g5 < 5; ++g5) {
            s0 += ptv[g5][d0];
            s1 += ptv[g5][d0 + 1];
        }
        bf16x2 o = { (bf16_t)s0, (bf16_t)s1 };
        *(bf16x2*)(attn_out + (size_t)n * DIM + d0) = o;
    }
}

// ---------------------------------------------------------------------------
extern "C" void kernel_launch(void* const* d_in, const int* in_sizes, int n_in,
                              void* d_out, int out_size, void* d_ws, size_t ws_size,
                              hipStream_t stream)
{
    const float* query  = (const float*)d_in[0];
    const int*   pos    = (const int*)d_in[1];
    const float* fmaps  = (const float*)d_in[3];
    const float* nw     = (const float*)d_in[5];
    const float* nb     = (const float*)d_in[6];
    const float* wq     = (const float*)d_in[7];
    const float* wkv    = (const float*)d_in[8];
    const float* wout   = (const float*)d_in[9];
    float* out = (float*)d_out;

    const int Mkv = in_sizes[3] / DIM;  // B*total = 21760

    char* w = (char*)d_ws;
    auto alloc = [&](size_t bytes) { char* p = w; w += (bytes + 255) & ~(size_t)255; return p; };
    bf16_t* x_ln    = (bf16_t*)alloc((size_t)NQ * DIM * 2);
    float*  qproj   = (float*) alloc((size_t)NQ * DIM * 4);
    bf16_t* attn_o  = (bf16_t*)alloc((size_t)NQ * DIM * 2);
    bf16_t* kvm     = (bf16_t*)alloc((size_t)Mkv * 2 * DIM * 2);
    bf16_t* fm_bf   = (bf16_t*)alloc((size_t)Mkv * DIM * 2);
    bf16_t* wq_bf   = (bf16_t*)alloc((size_t)DIM * DIM * 2);
    bf16_t* wkv_bf  = (bf16_t*)alloc((size_t)2 * DIM * DIM * 2);
    bf16_t* wout_bf = (bf16_t*)alloc((size_t)DIM * DIM * 2);
    float2* tabS    = (float2*)alloc(512 * 8);
    float2* tabL    = (float2*)alloc(32 * 8);

    const int nfm = Mkv * DIM / 4 / 256;   // fmaps cvt blocks (8160)
    prep_kernel<<<nfm + 577, 256, 0, stream>>>(
        fmaps, fm_bf, nfm, wq, wkv, wout, wq_bf, wkv_bf, wout_bf, tabS, tabL);
    ln_kernel<<<NQ, 64, 0, stream>>>(query, nw, nb, x_ln);
    gemm_bf16<0, 64><<<dim3(DIM / 64, NQ / 64), 256, 0, stream>>>(
        x_ln, wq_bf, (void*)qproj, nullptr, NQ, DIM, DIM);
    gemm_bf16<2, 128><<<dim3((2 * DIM) / 128, Mkv / 128), 256, 0, stream>>>(
        fm_bf, wkv_bf, (void*)kvm, nullptr, Mkv, 2 * DIM, DIM);
    rope_k_kernel<<<(Mkv * NHEAD + 255) / 256, 256, 0, stream>>>(kvm, tabS, tabL, Mkv);
    attn_kernel<<<NQ, 256, 0, stream>>>(qproj, pos, kvm, tabS, tabL, attn_o);
    gemm_bf16<1, 64><<<dim3(DIM / 64, NQ / 64), 256, 0, stream>>>(
        attn_o, wout_bf, (void*)out, query, NQ, DIM, DIM);
}

// Round 15
// 94.571 us; speedup vs baseline: 1.0366x; 1.0366x over previous
//
#include <hip/hip_runtime.h>
#include <hip/hip_bf16.h>

typedef __bf16 bf16_t;
typedef __attribute__((ext_vector_type(4))) float f32x4;
typedef __attribute__((ext_vector_type(8))) __bf16 bf16x8;
typedef __attribute__((ext_vector_type(4))) __bf16 bf16x4;
typedef __attribute__((ext_vector_type(2))) __bf16 bf16x2;

#define NQ    1024
#define DIM   384
#define NHEAD 8
#define HDIM  48
#define HALFD 24
#define NKEY  196
#define TOTAL 5440   // 64*64 + 32*32 + 16*16 + 8*8

typedef __attribute__((address_space(1))) void gas_void;
typedef __attribute__((address_space(3))) void las_void;
__device__ __forceinline__ void gload16(const void* g, void* l) {
    __builtin_amdgcn_global_load_lds((gas_void*)g, (las_void*)l, 16, 0, 0);
}

// ---------------------------------------------------------------------------
// prep: fmaps fp32->bf16 (blocks [0,nfm)), weights (nfm..nfm+575),
// sincos tables (nfm+576), fused LayerNorm (nfm+577 .. nfm+577+255, 4 rows/blk)
// ---------------------------------------------------------------------------
__global__ __launch_bounds__(256) void prep_kernel(
    const float* __restrict__ fmaps, bf16_t* __restrict__ fm_bf, int nfm,
    const float* __restrict__ wq, const float* __restrict__ wkv,
    const float* __restrict__ wout, bf16_t* __restrict__ wq_bf,
    bf16_t* __restrict__ wkv_bf, bf16_t* __restrict__ wout_bf,
    float2* __restrict__ tabS, float2* __restrict__ tabL,
    const float* __restrict__ query, const float* __restrict__ nw,
    const float* __restrict__ nb, bf16_t* __restrict__ x_ln)
{
    int bid = blockIdx.x;
    if (bid < nfm) {
        int i = bid * 256 + threadIdx.x;
        float4 v = ((const float4*)fmaps)[i];
        bf16x4 o = { (bf16_t)v.x, (bf16_t)v.y, (bf16_t)v.z, (bf16_t)v.w };
        ((bf16x4*)fm_bf)[i] = o;
        return;
    }
    int wb = bid - nfm;
    if (wb < 576) {
        int i = wb * 256 + threadIdx.x;
        const float* src; bf16_t* dst; int off;
        if (i < 36864)       { src = wq;   dst = wq_bf;   off = i; }
        else if (i < 110592) { src = wkv;  dst = wkv_bf;  off = i - 36864; }
        else                 { src = wout; dst = wout_bf; off = i - 110592; }
        float4 v = ((const float4*)src)[off];
        bf16x4 o = { (bf16_t)v.x, (bf16_t)v.y, (bf16_t)v.z, (bf16_t)v.w };
        ((bf16x4*)dst)[off] = o;
        return;
    }
    if (wb == 576) {
        int t = threadIdx.x;
        if (t < 512) {
            int i = t >> 3, f = t & 7;
            float fr = powf(10.f, -(float)f / 8.f);
            float s, c; sincosf((float)i * fr, &s, &c);
            tabS[t] = make_float2(c, s);
        } else if (t < 544) {
            int u = t - 512; int l = u >> 3, f = u & 7;
            float fr = powf(10.f, (float)f / 8.f);
            float s, c; sincosf((float)l * fr, &s, &c);
            tabL[u] = make_float2(c, s);
        }
        return;
    }
    // LayerNorm: 4 rows per block, one wave per row
    {
        int n = (wb - 577) * 4 + (threadIdx.x >> 6);
        int lane = threadIdx.x & 63;
        const float* row = query + (size_t)n * DIM;
        float v[6], s = 0.f, s2 = 0.f;
#pragma unroll
        for (int i = 0; i < 6; ++i) {
            v[i] = row[lane + i * 64];
            s += v[i]; s2 += v[i] * v[i];
        }
#pragma unroll
        for (int m = 32; m; m >>= 1) { s += __shfl_xor(s, m); s2 += __shfl_xor(s2, m); }
        float mu  = s * (1.f / DIM);
        float var = s2 * (1.f / DIM) - mu * mu;
        float rs  = rsqrtf(var + 1e-5f);
#pragma unroll
        for (int i = 0; i < 6; ++i) {
            int d = lane + i * 64;
            x_ln[(size_t)n * DIM + d] = (bf16_t)((v[i] - mu) * rs * nw[d] + nb[d]);
        }
    }
}

// ---------------------------------------------------------------------------
// bf16 NT GEMM, BK=32 double-buffered prefetch (T3 minimum 2-phase):
// stage tile t+1 BEFORE computing tile t; one barrier per K-step (its vmcnt
// drain lands after compute has covered the load latency). LDS same 32KB as
// the single-buffer BK=64 version -> occupancy preserved.
// EPI: 0 = fp32 C, 1 = fp32 C + resid, 2 = bf16 C.  BT = 128 or 64.
// ---------------------------------------------------------------------------
template<int EPI, int BT>
__global__ __launch_bounds__(256) void gemm_bf16(
    const bf16_t* __restrict__ A, const bf16_t* __restrict__ Bw,
    void* __restrict__ Cp, const float* __restrict__ resid,
    int M, int Nout, int K)
{
    constexpr int FRG = BT / 32;
    constexpr int WT  = BT / 2;
    constexpr int BK  = 32;
    constexpr int CPT = (BT * BK) / (256 * 8);   // 16B chunks per thread per matrix
    __shared__ bf16_t As[2][BT * BK];
    __shared__ bf16_t Bs[2][BT * BK];
    const int tid = threadIdx.x;

    const int bid = blockIdx.y * gridDim.x + blockIdx.x;
    const int nwg = gridDim.x * gridDim.y;
    const int qq = nwg >> 3, rr8 = nwg & 7;
    const int xcd = bid & 7, loc = bid >> 3;
    const int swz = (xcd < rr8 ? xcd * (qq + 1) : rr8 * (qq + 1) + (xcd - rr8) * qq) + loc;
    const int bm = swz / gridDim.x, bn = swz % gridDim.x;

    const int wave = tid >> 6, lane = tid & 63;
    const int wr   = wave >> 1, wc = wave & 1;
    const int fr   = lane & 15, g = lane >> 4;

    const bf16_t* Ab = A  + (size_t)bm * BT * K;
    const bf16_t* Bb = Bw + (size_t)bn * BT * K;

    auto stage = [&](int buf, int kt) {
#pragma unroll
        for (int it = 0; it < CPT; ++it) {
            int chunk = it * 256 + tid;
            int row = chunk >> 2, c4 = chunk & 3;
            int sc4 = c4 ^ ((row >> 1) & 3);
            gload16(Ab + (size_t)row * K + kt + sc4 * 8, &As[buf][chunk * 8]);
            gload16(Bb + (size_t)row * K + kt + sc4 * 8, &Bs[buf][chunk * 8]);
        }
    };

    f32x4 acc[FRG][FRG];
#pragma unroll
    for (int i = 0; i < FRG; ++i)
#pragma unroll
        for (int j = 0; j < FRG; ++j) acc[i][j] = (f32x4){0.f, 0.f, 0.f, 0.f};

    stage(0, 0);
    __syncthreads();
    int cur = 0;
    const int NT = K / BK;
    for (int t = 0; t < NT; ++t) {
        if (t + 1 < NT) stage(cur ^ 1, (t + 1) * BK);   // prefetch next tile
        bf16x8 af[FRG], bfr[FRG];
#pragma unroll
        for (int mi = 0; mi < FRG; ++mi) {
            int row = wr * WT + mi * 16 + fr;
            int c = g ^ ((row >> 1) & 3);
            af[mi] = *(const bf16x8*)(&As[cur][row * BK + c * 8]);
        }
#pragma unroll
        for (int ni = 0; ni < FRG; ++ni) {
            int row = wc * WT + ni * 16 + fr;
            int c = g ^ ((row >> 1) & 3);
            bfr[ni] = *(const bf16x8*)(&Bs[cur][row * BK + c * 8]);
        }
#pragma unroll
        for (int mi = 0; mi < FRG; ++mi)
#pragma unroll
            for (int ni = 0; ni < FRG; ++ni)
                acc[mi][ni] = __builtin_amdgcn_mfma_f32_16x16x32_bf16(
                    af[mi], bfr[ni], acc[mi][ni], 0, 0, 0);
        __syncthreads();   // drains prefetch; next tile ready
        cur ^= 1;
    }

    const int r0 = g << 2;
#pragma unroll
    for (int mi = 0; mi < FRG; ++mi) {
#pragma unroll
        for (int ni = 0; ni < FRG; ++ni) {
#pragma unroll
            for (int e = 0; e < 4; ++e) {
                int row = bm * BT + wr * WT + mi * 16 + r0 + e;
                int col = bn * BT + wc * WT + ni * 16 + fr;
                float v = acc[mi][ni][e];
                if (EPI == 2) {
                    ((bf16_t*)Cp)[(size_t)row * Nout + col] = (bf16_t)v;
                } else {
                    if (EPI == 1) v += resid[(size_t)row * Nout + col];
                    ((float*)Cp)[(size_t)row * Nout + col] = v;
                }
            }
        }
    }
}

// ---------------------------------------------------------------------------
// Pre-rotate the k-half of the kv map in place. One thread per (row, head).
// ---------------------------------------------------------------------------
__global__ __launch_bounds__(256) void rope_k_kernel(
    bf16_t* __restrict__ kvm, const float2* __restrict__ tabS,
    const float2* __restrict__ tabL, int Mkv)
{
    int t = blockIdx.x * 256 + threadIdx.x;
    if (t >= Mkv * NHEAD) return;
    int row = t >> 3, h = t & 7;

    int rr = row % TOTAL;
    int l, i, j;
    if (rr < 4096)      { l = 0; i = rr >> 6;               j = rr & 63; }
    else if (rr < 5120) { l = 1; int u = rr - 4096; i = u >> 5; j = u & 31; }
    else if (rr < 5376) { l = 2; int u = rr - 5120; i = u >> 4; j = u & 15; }
    else                { l = 3; int u = rr - 5376; i = u >> 3; j = u & 7;  }

    bf16_t* base = kvm + (size_t)row * (2 * DIM) + h * HDIM;
    bf16x8 xa[3], xb[3];
#pragma unroll
    for (int k = 0; k < 3; ++k) {
        xa[k] = *(const bf16x8*)(base + 8 * k);
        xb[k] = *(const bf16x8*)(base + HALFD + 8 * k);
    }
#pragma unroll
    for (int d = 0; d < HALFD; ++d) {
        float2 cs = (d < 8) ? tabS[i * 8 + d]
                  : (d < 16) ? tabS[j * 8 + (d - 8)]
                             : tabL[l * 8 + (d - 16)];
        float x1 = (float)xa[d >> 3][d & 7];
        float x2 = (float)xb[d >> 3][d & 7];
        xa[d >> 3][d & 7] = (bf16_t)(x1 * cs.x - x2 * cs.y);
        xb[d >> 3][d & 7] = (bf16_t)(x1 * cs.y + x2 * cs.x);
    }
#pragma unroll
    for (int k = 0; k < 3; ++k) {
        *(bf16x8*)(base + 8 * k)         = xa[k];
        *(bf16x8*)(base + HALFD + 8 * k) = xb[k];
    }
}

// ---------------------------------------------------------------------------
// Attention: one block (256 threads) per query — R13-proven (best measured).
// XCD-chunked query remap; strided score loop; 32-lane softmax; 16B V phase.
// ---------------------------------------------------------------------------
__global__ __launch_bounds__(256) void attn_kernel(
    const float* __restrict__ qproj,   // (N,384) pre-RoPE fp32
    const int*   __restrict__ pos,     // (N,4) b,i,j,l
    const bf16_t* __restrict__ kvm,    // (B*total, 768) bf16, k pre-rotated
    const float2* __restrict__ tabS, const float2* __restrict__ tabL,
    bf16_t* __restrict__ attn_out)     // (N,384) bf16
{
    __shared__ float qs[DIM];
    __shared__ float sc[NHEAD * NKEY];
    __shared__ int   flatL[NKEY], validL[NKEY];
    __shared__ float ptv[5][DIM];

    const int bid = blockIdx.x, tid = threadIdx.x;
    const int n = ((bid & 7) << 7) | (bid >> 3);   // XCD-chunked remap
    const int b  = pos[n * 4 + 0];
    const int qi = pos[n * 4 + 1];
    const int qj = pos[n * 4 + 2];
    const int ql = pos[n * 4 + 3];

    // q RoPE -> qs (threads 0..191)
    if (tid < NHEAD * HALFD) {
        int h = tid / HALFD, d = tid - (tid / HALFD) * HALFD;
        float2 cs = (d < 8) ? tabS[qi * 8 + d]
                  : (d < 16) ? tabS[qj * 8 + (d - 8)]
                             : tabL[ql * 8 + (d - 16)];
        float x1 = qproj[(size_t)n * DIM + h * HDIM + d];
        float x2 = qproj[(size_t)n * DIM + h * HDIM + HALFD + d];
        qs[h * HDIM + d]         = x1 * cs.x - x2 * cs.y;
        qs[h * HDIM + HALFD + d] = x1 * cs.y + x2 * cs.x;
    }

    // per-key geometry, pure integer: center = floor((q+0.5)*2^(ql-l))
    if (tid < NKEY) {
        int kk = tid;
        int l = kk / 49, rem = kk - l * 49;
        int a = rem / 7, bb2 = rem - a * 7;
        int Hl = 64 >> l;
        int off = (l == 0) ? 0 : (l == 1) ? 4096 : (l == 2) ? 5120 : 5376;
        int e = ql - l;
        int ti = 2 * qi + 1, tj = 2 * qj + 1;
        int ci = (e >= 1) ? (ti << (e - 1)) : (ti >> (1 - e));
        int cj = (e >= 1) ? (tj << (e - 1)) : (tj >> (1 - e));
        int ii = ci + a - 3, jj = cj + bb2 - 3;
        int valid = (ii >= 0) && (ii < Hl) && (jj >= 0) && (jj < Hl);
        ii = min(max(ii, 0), Hl - 1); jj = min(max(jj, 0), Hl - 1);
        flatL[kk]  = off + ii * Hl + jj;
        validL[kk] = valid;
    }
    __syncthreads();

    const size_t bbase = (size_t)b * TOTAL;

    // scores: 8 heads x 196 keys
    for (int idx = tid; idx < NHEAD * NKEY; idx += 256) {
        int h = idx / NKEY, kk = idx - h * NKEY;
        const bf16_t* krow = kvm + (bbase + (size_t)flatL[kk]) * (2 * DIM) + h * HDIM;
        bf16x8 kv[6];
#pragma unroll
        for (int i = 0; i < 6; ++i) kv[i] = *(const bf16x8*)(krow + i * 8);
        float dot = 0.f;
#pragma unroll
        for (int i = 0; i < 6; ++i)
#pragma unroll
            for (int e = 0; e < 8; ++e)
                dot += (float)kv[i][e] * qs[h * HDIM + i * 8 + e];
        float score = dot * 0.14433756729740643f;  // 1/sqrt(48)
        if (!validL[kk]) score = -1e9f;
        sc[h * NKEY + kk] = score;
    }
    __syncthreads();

    // softmax: head h handled by threads [h*32, h*32+32)
    {
        int h = tid >> 5, lg = tid & 31;
        float mx = -1e30f;
        for (int j = lg; j < NKEY; j += 32) mx = fmaxf(mx, sc[h * NKEY + j]);
#pragma unroll
        for (int m = 16; m; m >>= 1) mx = fmaxf(mx, __shfl_xor(mx, m));
        float sum = 0.f;
        for (int j = lg; j < NKEY; j += 32) {
            float e = __expf(sc[h * NKEY + j] - mx);
            sc[h * NKEY + j] = e; sum += e;
        }
#pragma unroll
        for (int m = 16; m; m >>= 1) sum += __shfl_xor(sum, m);
        float inv = 1.f / sum;
        for (int j = lg; j < NKEY; j += 32) sc[h * NKEY + j] *= inv;
    }
    __syncthreads();

    // V accumulation: 240 threads = 5 key-groups x 48 dim-octets (16B loads)
    if (tid < 240) {
        int g5 = tid / 48, o = tid - (tid / 48) * 48;  // key-group, dim-octet
        int h = o / 6;                                  // head of this octet
        float a[8];
#pragma unroll
        for (int e = 0; e < 8; ++e) a[e] = 0.f;
        const float* sch = sc + h * NKEY;
#pragma unroll 4
        for (int kk = g5; kk < NKEY; kk += 5) {
            float w = sch[kk];
            bf16x8 vv = *(const bf16x8*)(kvm + (bbase + (size_t)flatL[kk]) * (2 * DIM)
                                         + DIM + 8 * o);
#pragma unroll
            for (int e = 0; e < 8; ++e) a[e] += w * (float)vv[e];
        }
        float4 lo = { a[0], a[1], a[2], a[3] };
        float4 hi = { a[4], a[5], a[6], a[7] };
        *(float4*)(&ptv[g5][8 * o])     = lo;
        *(float4*)(&ptv[g5][8 * o + 4]) = hi;
    }
    __syncthreads();

    // final reduce over key-groups: 192 threads x 2 dims
    if (tid < 192) {
        int d0 = 2 * tid;
        float s0 = 0.f, s1 = 0.f;
#pragma unroll
        for (int g5 = 0; g5 < 5; ++g5) {
            s0 += ptv[g5][d0];
            s1 += ptv[g5][d0 + 1];
        }
        bf16x2 o = { (bf16_t)s0, (bf16_t)s1 };
        *(bf16x2*)(attn_out + (size_t)n * DIM + d0) = o;
    }
}

// ---------------------------------------------------------------------------
extern "C" void kernel_launch(void* const* d_in, const int* in_sizes, int n_in,
                              void* d_out, int out_size, void* d_ws, size_t ws_size,
                              hipStream_t stream)
{
    const float* query  = (const float*)d_in[0];
    const int*   pos    = (const int*)d_in[1];
    const float* fmaps  = (const float*)d_in[3];
    const float* nw     = (const float*)d_in[5];
    const float* nb     = (const float*)d_in[6];
    const float* wq     = (const float*)d_in[7];
    const float* wkv    = (const float*)d_in[8];
    const float* wout   = (const float*)d_in[9];
    float* out = (float*)d_out;

    const int Mkv = in_sizes[3] / DIM;  // B*total = 21760

    char* w = (char*)d_ws;
    auto alloc = [&](size_t bytes) { char* p = w; w += (bytes + 255) & ~(size_t)255; return p; };
    bf16_t* x_ln    = (bf16_t*)alloc((size_t)NQ * DIM * 2);
    float*  qproj   = (float*) alloc((size_t)NQ * DIM * 4);
    bf16_t* attn_o  = (bf16_t*)alloc((size_t)NQ * DIM * 2);
    bf16_t* kvm     = (bf16_t*)alloc((size_t)Mkv * 2 * DIM * 2);
    bf16_t* fm_bf   = (bf16_t*)alloc((size_t)Mkv * DIM * 2);
    bf16_t* wq_bf   = (bf16_t*)alloc((size_t)DIM * DIM * 2);
    bf16_t* wkv_bf  = (bf16_t*)alloc((size_t)2 * DIM * DIM * 2);
    bf16_t* wout_bf = (bf16_t*)alloc((size_t)DIM * DIM * 2);
    float2* tabS    = (float2*)alloc(512 * 8);
    float2* tabL    = (float2*)alloc(32 * 8);

    const int nfm = Mkv * DIM / 4 / 256;   // fmaps cvt blocks (8160)
    prep_kernel<<<nfm + 577 + 256, 256, 0, stream>>>(
        fmaps, fm_bf, nfm, wq, wkv, wout, wq_bf, wkv_bf, wout_bf, tabS, tabL,
        query, nw, nb, x_ln);
    gemm_bf16<0, 64><<<dim3(DIM / 64, NQ / 64), 256, 0, stream>>>(
        x_ln, wq_bf, (void*)qproj, nullptr, NQ, DIM, DIM);
    gemm_bf16<2, 128><<<dim3((2 * DIM) / 128, Mkv / 128), 256, 0, stream>>>(
        fm_bf, wkv_bf, (void*)kvm, nullptr, Mkv, 2 * DIM, DIM);
    rope_k_kernel<<<(Mkv * NHEAD + 255) / 256, 256, 0, stream>>>(kvm, tabS, tabL, Mkv);
    attn_kernel<<<NQ, 256, 0, stream>>>(qproj, pos, kvm, tabS, tabL, attn_o);
    gemm_bf16<1, 64><<<dim3(DIM / 64, NQ / 64), 256, 0, stream>>>(
        attn_o, wout_bf, (void*)out, query, NQ, DIM, DIM);
}